// Round 8
// baseline (191.825 us; speedup 1.0000x reference)
//
#include <hip/hip_runtime.h>
#include <hip/hip_bf16.h>

typedef __bf16 bf16x8 __attribute__((ext_vector_type(8)));
typedef short s16x4 __attribute__((ext_vector_type(4)));
typedef short s16x8 __attribute__((ext_vector_type(8)));
typedef float f32x4 __attribute__((ext_vector_type(4)));
typedef unsigned short u16x8 __attribute__((ext_vector_type(8)));

#define MFMA_K32(a, b, c) __builtin_amdgcn_mfma_f32_16x16x32_bf16(a, b, c, 0, 0, 0)

// 16x16x16 bf16 MFMA; builtin exists only in device pass.
static __device__ __forceinline__ f32x4 mfma_k16(s16x4 a, s16x4 b, f32x4 c) {
#ifdef __HIP_DEVICE_COMPILE__
    return __builtin_amdgcn_mfma_f32_16x16x16bf16_1k(a, b, c, 0, 0, 0);
#else
    return c;
#endif
}

static __device__ __forceinline__ float fast_exp2(float x) {
#ifdef __HIP_DEVICE_COMPILE__
    return __builtin_amdgcn_exp2f(x);
#else
    return x;
#endif
}

// async global->LDS, 16B per lane; lds dest = wave-uniform base + lane*16
#define GLL16(gp, lp)                                              \
    __builtin_amdgcn_global_load_lds(                              \
        (const __attribute__((address_space(1))) void*)(gp),       \
        (__attribute__((address_space(3))) void*)(lp), 16, 0, 0)

// round-to-nearest-even fp32 -> bf16 (finite inputs only)
static __device__ __forceinline__ unsigned short f2bf(float f) {
    unsigned int u = __float_as_uint(f);
    u += 0x7fffu + ((u >> 16) & 1u);
    return (unsigned short)(u >> 16);
}

// packed fp32x2 -> bf16x2 (RNE) via gfx950 v_cvt_pk_bf16_f32 when available
static __device__ __forceinline__ unsigned int cvtpk_bf16(float lo, float hi) {
#if defined(__HIP_DEVICE_COMPILE__) && __has_builtin(__builtin_amdgcn_cvt_pk_bf16_f32)
    typedef __bf16 bf16x2 __attribute__((ext_vector_type(2)));
    bf16x2 r = __builtin_amdgcn_cvt_pk_bf16_f32(lo, hi);
    return __builtin_bit_cast(unsigned int, r);
#else
    return (unsigned int)f2bf(lo) | ((unsigned int)f2bf(hi) << 16);
#endif
}

#define LOG2E 1.44269504088896340736f

// ---------------------------------------------------------------------------
// Fused prep: transpose+cast w_qkv and w_out, rmsnorm x -> xn (bf16).
// ---------------------------------------------------------------------------
__global__ __launch_bounds__(256) void prep_k(
    const float* __restrict__ x, const float* __restrict__ gamma,
    const float* __restrict__ w_qkv, const float* __restrict__ w_out,
    unsigned short* __restrict__ xn, unsigned short* __restrict__ wtq,
    unsigned short* __restrict__ wto) {
    __shared__ float sm[32][33];
    int bid = blockIdx.x, tid = threadIdx.x;
    if (bid < 4096) {  // transpose paths (block-uniform branch)
        const float* in;
        unsigned short* out;
        int R = 1024, C, bx, by;
        if (bid < 3072) { in = w_qkv; out = wtq; C = 3072; bx = bid % 96; by = bid / 96; }
        else { int b2 = bid - 3072; in = w_out; out = wto; C = 1024; bx = b2 % 32; by = b2 / 32; }
        int c0 = bx * 32, r0 = by * 32;
        int tr = tid >> 5, tc = tid & 31;
#pragma unroll
        for (int i = 0; i < 4; i++)
            sm[tr + i * 8][tc] = in[(size_t)(r0 + tr + i * 8) * C + c0 + tc];
        __syncthreads();
#pragma unroll
        for (int i = 0; i < 4; i++)
            out[(size_t)(c0 + tr + i * 8) * R + r0 + tc] = f2bf(sm[tc][tr + i * 8]);
    } else {  // rmsnorm
        int row = bid - 4096;
        const float* xr = x + (size_t)row * 1024;
        float4 v = *(const float4*)(xr + tid * 4);
        float ss = v.x * v.x + v.y * v.y + v.z * v.z + v.w * v.w;
#pragma unroll
        for (int off = 1; off < 64; off <<= 1) ss += __shfl_xor(ss, off, 64);
        if ((tid & 63) == 0) sm[0][tid >> 6] = ss;
        __syncthreads();
        float tot = sm[0][0] + sm[0][1] + sm[0][2] + sm[0][3];
        float f = 32.0f / fmaxf(sqrtf(tot), 1e-12f);  // sqrt(1024)=32
        float4 g = *(const float4*)(gamma + tid * 4);
        uint2 o;
        o.x = cvtpk_bf16(v.x * f * g.x, v.y * f * g.y);
        o.y = cvtpk_bf16(v.z * f * g.z, v.w * f * g.w);
        *(uint2*)(xn + (size_t)row * 1024 + tid * 4) = o;
    }
}

// ---------------------------------------------------------------------------
// GEMM (m97 structure): C[M,N] = A[M,K] * BT[N,K]^T, bf16 in, fp32 acc.
// MODE 0: fp32 store. MODE 1: qkv epilogue. V is stored transposed
// [bh][d][key'] with keys PRE-SWIZZLED per 64-block: token t -> position
// ((t>>2)&3)*16 + (t>>4)*4 + (t&3), so attention reads K16 A-fragments as
// contiguous b128 (two fragments per read).
// ---------------------------------------------------------------------------
template <int MODE, int BM>
__global__ __launch_bounds__(256) void gemm_bt_k(
    const unsigned short* __restrict__ A, const unsigned short* __restrict__ BT,
    float* __restrict__ C, unsigned short* __restrict__ qw,
    unsigned short* __restrict__ kw, unsigned short* __restrict__ vw,
    int M, int N, int K) {
    constexpr int RT = 4;
    constexpr int CT = (BM == 128) ? 4 : 2;
    __shared__ unsigned short As[BM][32];
    __shared__ unsigned short Bs[128][32];
    int tid = threadIdx.x;
    int wave = tid >> 6, lane = tid & 63, quad = lane >> 4, l16 = lane & 15;
    int wrb, wcb;
    if constexpr (BM == 128) { wrb = (wave >> 1) * 64; wcb = (wave & 1) * 64; }
    else { wrb = 0; wcb = wave * 32; }
    int m0 = blockIdx.y * BM, n0 = blockIdx.x * 128;
    int lrow = lane >> 2, lcol = (lane & 3) * 8;  // lane -> (row,col) in 16x32 chunk
    const unsigned short *Ag0, *Ag1 = nullptr;
    if constexpr (BM == 128) {
        Ag0 = A + (size_t)(m0 + wave * 32 + lrow) * K + lcol;
        Ag1 = A + (size_t)(m0 + wave * 32 + 16 + lrow) * K + lcol;
    } else {
        Ag0 = A + (size_t)(m0 + wave * 16 + lrow) * K + lcol;
    }
    const unsigned short* Bg0 = BT + (size_t)(n0 + wave * 32 + lrow) * K + lcol;
    const unsigned short* Bg1 = BT + (size_t)(n0 + wave * 32 + 16 + lrow) * K + lcol;
    f32x4 acc[RT][CT] = {};
    for (int k0 = 0; k0 < K; k0 += 32) {
        __syncthreads();  // prior ds_reads done before overwrite
        if constexpr (BM == 128) {
            GLL16(Ag0 + k0, &As[wave * 32][0]);
            GLL16(Ag1 + k0, &As[wave * 32 + 16][0]);
        } else {
            GLL16(Ag0 + k0, &As[wave * 16][0]);
        }
        GLL16(Bg0 + k0, &Bs[wave * 32][0]);
        GLL16(Bg1 + k0, &Bs[wave * 32 + 16][0]);
        __syncthreads();  // drains vmcnt: staging complete
        bf16x8 af[RT], bfr[CT];
#pragma unroll
        for (int t = 0; t < RT; t++)
            af[t] = *(const bf16x8*)&As[wrb + t * 16 + l16][quad * 8];
#pragma unroll
        for (int t = 0; t < CT; t++)
            bfr[t] = *(const bf16x8*)&Bs[wcb + t * 16 + l16][quad * 8];
#pragma unroll
        for (int rt = 0; rt < RT; rt++)
#pragma unroll
            for (int ct = 0; ct < CT; ct++)
                acc[rt][ct] = MFMA_K32(af[rt], bfr[ct], acc[rt][ct]);
    }
#pragma unroll
    for (int rt = 0; rt < RT; rt++) {
        int mb = m0 + wrb + rt * 16 + quad * 4;
        int b = mb >> 11, nn = mb & 2047;
#pragma unroll
        for (int ct = 0; ct < CT; ct++) {
            int col = n0 + wcb + ct * 16 + l16;
            if (MODE == 0) {
#pragma unroll
                for (int r = 0; r < 4; r++)
                    C[(size_t)(mb + r) * N + col] = acc[rt][ct][r];
            } else {
                int sec = col >> 10, ci = col & 1023;
                int hh = ci >> 6, dd = ci & 63;
                int bh = b * 16 + hh;
                if (sec == 0) {
#pragma unroll
                    for (int r = 0; r < 4; r++)
                        qw[((size_t)bh * 2048 + nn + r) * 64 + dd] =
                            f2bf(acc[rt][ct][r] * (0.125f * LOG2E));
                } else if (sec == 1) {
#pragma unroll
                    for (int r = 0; r < 4; r++)
                        kw[((size_t)bh * 2048 + nn + r) * 64 + dd] = f2bf(acc[rt][ct][r]);
                } else {
                    uint2 pk;
                    pk.x = cvtpk_bf16(acc[rt][ct][0], acc[rt][ct][1]);
                    pk.y = cvtpk_bf16(acc[rt][ct][2], acc[rt][ct][3]);
                    // swizzle token within its 64-block: t -> (quad)(ct)(r)
                    int sb = (nn & ~63) | (((nn >> 2) & 3) << 4) | (((nn >> 4) & 3) << 2);
                    *(uint2*)&vw[((size_t)bh * 64 + dd) * 2048 + sb] = pk;
                }
            }
        }
    }
}

// ---------------------------------------------------------------------------
// Causal flash attention: 128-KEY tiles (softmax fixed costs, barriers, and
// loop overhead amortized 2x vs 64-key). St = K*Q^T (K32), Ot += V^T*P^T
// (K16, P in registers). V^T is key-swizzled so av = b128 reads (2 frags).
// One 64-row q-tile per block (4 waves x 16 rows); grid x=bh (XCD=bh%8 ->
// K/V L2-resident), y->qt=31-y (LPT). Double-buffered K/V, ONE barrier per
// 128 keys. LDS 71.7 KB -> 2 blocks/CU.
// ---------------------------------------------------------------------------
__global__ __launch_bounds__(256) void attn_k(
    const unsigned short* __restrict__ q, const unsigned short* __restrict__ k,
    const unsigned short* __restrict__ vt, unsigned short* __restrict__ o) {
    __shared__ unsigned short Ks[2][128][72];   // [buf][key][d]      36,864 B
    __shared__ unsigned short Vt[2][64][136];   // [buf][d][key-sw]   34,816 B
    int bh = blockIdx.x;
    int qt = 31 - (int)blockIdx.y;  // heavy-first LPT order
    int tid = threadIdx.x, wave = tid >> 6, lane = tid & 63;
    int quad = lane >> 4, l16 = lane & 15;
    int b = bh >> 4, h = bh & 15;
    const unsigned short* qg = q + (size_t)bh * 2048 * 64;
    const unsigned short* kg = k + (size_t)bh * 2048 * 64;
    const unsigned short* vg = vt + (size_t)bh * 64 * 2048;
    // staging coords: K 128 rows x 64 d (64 B/thread), V 64 d x 128 keys
    int krow = tid >> 1, kcol = (tid & 1) * 32;
    int vrow = tid >> 2, vcol = (tid & 3) * 32;
    int q0w = qt * 64 + wave * 16;
    bf16x8 bq[2];  // Q^T B-operand: [k=d=ks*32+quad*8+j][n=qrow=l16]
#pragma unroll
    for (int ks = 0; ks < 2; ks++)
        bq[ks] = *(const bf16x8*)&qg[(size_t)(q0w + l16) * 64 + ks * 32 + quad * 8];
    f32x4 ot[4] = {};                 // Ot C-layout: [d=dt*16+quad*4+r][qrow=l16]
    float mrun = -1e38f, lrun = 0.f;  // per-lane state for qrow=q0w+l16
    int nkt = (qt >> 1) + 1;          // 128-key tiles in causal prefix
    u16x8 pk[4], pv[4];               // prefetch registers (32 VGPRs)
    {  // preload tile 0
        const unsigned short* kp = kg + (size_t)krow * 64 + kcol;
        const unsigned short* vp = vg + (size_t)vrow * 2048 + vcol;
#pragma unroll
        for (int i = 0; i < 4; i++) {
            pk[i] = *(const u16x8*)(kp + i * 8);
            pv[i] = *(const u16x8*)(vp + i * 8);
        }
#pragma unroll
        for (int i = 0; i < 4; i++) {
            *(u16x8*)&Ks[0][krow][kcol + i * 8] = pk[i];
            *(u16x8*)&Vt[0][vrow][vcol + i * 8] = pv[i];
        }
    }
    __syncthreads();
    for (int kt = 0; kt < nkt; kt++) {
        int cb = kt & 1;
        bool pf = (kt + 1 < nkt);
        if (pf) {  // issue next tile's global loads early
            const unsigned short* kp = kg + (size_t)((kt + 1) * 128 + krow) * 64 + kcol;
            const unsigned short* vp = vg + (size_t)vrow * 2048 + (kt + 1) * 128 + vcol;
#pragma unroll
            for (int i = 0; i < 4; i++) {
                pk[i] = *(const u16x8*)(kp + i * 8);
                pv[i] = *(const u16x8*)(vp + i * 8);
            }
        }
        // St[key=ct*16+quad*4+r][qrow=l16] = K . Q^T, 8 key-subtiles
        f32x4 sf[8];
#pragma unroll
        for (int ct = 0; ct < 8; ct++) {
            bf16x8 ak0 = *(const bf16x8*)&Ks[cb][ct * 16 + l16][quad * 8];
            bf16x8 ak1 = *(const bf16x8*)&Ks[cb][ct * 16 + l16][32 + quad * 8];
            f32x4 s = {};
            s = MFMA_K32(ak0, bq[0], s);
            s = MFMA_K32(ak1, bq[1], s);
            sf[ct] = s;
        }
        if (kt == nkt - 1) {  // diagonal (and, for even qt, over-reach) mask
            int qrow = q0w + l16;
            int keyb = kt * 128 + quad * 4;
#pragma unroll
            for (int ct = 0; ct < 8; ct++)
#pragma unroll
                for (int r = 0; r < 4; r++)
                    if (keyb + ct * 16 + r > qrow) sf[ct][r] = -1e30f;
        }
        // online softmax over 32 values/lane (exp2 domain)
        float mx = -1e30f;
#pragma unroll
        for (int ct = 0; ct < 8; ct++)
#pragma unroll
            for (int r = 0; r < 4; r++) mx = fmaxf(mx, sf[ct][r]);
        mx = fmaxf(mx, __shfl_xor(mx, 16, 64));
        mx = fmaxf(mx, __shfl_xor(mx, 32, 64));
        float mnew = fmaxf(mrun, mx);
        float al = fast_exp2(mrun - mnew);
        mrun = mnew;
        float rs = 0.f;
#pragma unroll
        for (int ct = 0; ct < 8; ct++)
#pragma unroll
            for (int r = 0; r < 4; r++) {
                float p = fast_exp2(sf[ct][r] - mnew);
                sf[ct][r] = p;
                rs += p;
            }
        rs += __shfl_xor(rs, 16, 64);
        rs += __shfl_xor(rs, 32, 64);
        lrun = lrun * al + rs;
        // P -> packed bf16 B-fragments for 16x16x16 (k=quad*4+j = C-layout)
        s16x4 bpr[8];
#pragma unroll
        for (int ct = 0; ct < 8; ct++) {
            uint2 u;
            u.x = cvtpk_bf16(sf[ct][0], sf[ct][1]);
            u.y = cvtpk_bf16(sf[ct][2], sf[ct][3]);
            bpr[ct] = __builtin_bit_cast(s16x4, u);
        }
        // rescale Ot only when some row saw a new max (rare in late tiles)
        if (__any(al < 1.0f)) {
#pragma unroll
            for (int dt = 0; dt < 4; dt++)
#pragma unroll
                for (int r = 0; r < 4; r++) ot[dt][r] *= al;
        }
        // Ot += V^T * P^T; swizzled V: one b128 = two K16 A-fragments
#pragma unroll
        for (int dt = 0; dt < 4; dt++) {
#pragma unroll
            for (int blk = 0; blk < 2; blk++)
#pragma unroll
                for (int p = 0; p < 2; p++) {
                    s16x8 av = *(const s16x8*)&Vt[cb][dt * 16 + l16]
                                                  [blk * 64 + quad * 16 + p * 8];
                    s16x4 lo = __builtin_shufflevector(av, av, 0, 1, 2, 3);
                    s16x4 hi = __builtin_shufflevector(av, av, 4, 5, 6, 7);
                    int ct = blk * 4 + p * 2;
                    ot[dt] = mfma_k16(lo, bpr[ct], ot[dt]);
                    ot[dt] = mfma_k16(hi, bpr[ct + 1], ot[dt]);
                }
        }
        if (pf) {  // write prefetched tile to the other buffer
#pragma unroll
            for (int i = 0; i < 4; i++) {
                *(u16x8*)&Ks[1 - cb][krow][kcol + i * 8] = pk[i];
                *(u16x8*)&Vt[1 - cb][vrow][vcol + i * 8] = pv[i];
            }
        }
        __syncthreads();  // single barrier per 128 keys
    }
    // epilogue: Ot C-layout -> o[(b*2048+qrow)*1024 + h*64 + d]
    float inv = 1.0f / lrun;
    size_t rowbase = ((size_t)b * 2048 + q0w + l16) * 1024 + h * 64;
#pragma unroll
    for (int dt = 0; dt < 4; dt++) {
        uint2 pk2;
        pk2.x = cvtpk_bf16(ot[dt][0] * inv, ot[dt][1] * inv);
        pk2.y = cvtpk_bf16(ot[dt][2] * inv, ot[dt][3] * inv);
        *(uint2*)&o[rowbase + dt * 16 + quad * 4] = pk2;
    }
}

extern "C" void kernel_launch(void* const* d_in, const int* in_sizes, int n_in,
                              void* d_out, int out_size, void* d_ws, size_t ws_size,
                              hipStream_t stream) {
    const float* x = (const float*)d_in[0];       // [2,2048,1024]
    const float* gamma = (const float*)d_in[1];   // [1024]
    const float* w_qkv = (const float*)d_in[2];   // [1024,3072]
    const float* w_out = (const float*)d_in[3];   // [1024,1024]
    float* out = (float*)d_out;                   // [2,2048,1024] fp32
    char* ws = (char*)d_ws;

    unsigned short* xn = (unsigned short*)(ws);              // 8 MB (reused as ao)
    unsigned short* wtq = (unsigned short*)(ws + 8388608);   // 6 MB  [3072][1024]
    unsigned short* wto = (unsigned short*)(ws + 14680064);  // 2 MB  [1024][1024]
    unsigned short* qw = (unsigned short*)(ws + 16777216);   // 8 MB  [32][2048][64]
    unsigned short* kw = (unsigned short*)(ws + 25165824);   // 8 MB  [32][2048][64]
    unsigned short* vw = (unsigned short*)(ws + 33554432);   // 8 MB  [32][64][2048] sw
    unsigned short* ao = xn;                                 // reuse after QKV GEMM

    prep_k<<<8192, 256, 0, stream>>>(x, gamma, w_qkv, w_out, xn, wtq, wto);
    gemm_bt_k<1, 128><<<dim3(24, 32), 256, 0, stream>>>(xn, wtq, nullptr, qw, kw, vw,
                                                        4096, 3072, 1024);
    attn_k<<<dim3(32, 32), 256, 0, stream>>>(qw, kw, vw, ao);
    gemm_bt_k<0, 64><<<dim3(8, 64), 256, 0, stream>>>(ao, wto, out, nullptr, nullptr,
                                                      nullptr, 4096, 1024, 1024);
}